// Round 10
// baseline (358.884 us; speedup 1.0000x reference)
//
#include <hip/hip_runtime.h>

// ViTMoEAttention: B=32,S=257,D=1024,H=16,HD=64,E=8,R=16,K=2
// Round 17:
//  - R16 worked (324.8us; qkv 83us). qkv Occupancy=32% shows only ONE
//    1024-thr block resident/CU (despite 64KB LDS) -> 1.55 ragged rounds,
//    no co-resident block to hide the vmcnt(0) drain.
//  - This round: gemm_qkv re-tiled to 256x128, 512 thr / 8 waves (4Mx2N of
//    64x64, acc=64 VGPR), 2x24KB LDS (48KB) -> 3 blocks/CU, grid 33x24=792
//    ~= 3.09/CU single round. Identical structure to the verified R14
//    gemm_o kernel (same loop/staging/tail mapping), with qkv addressing
//    and 128-col q/k/v epilogues (static acc indices everywhere).
//  - Falsifier: occupancy stays ~32% -> residency capped elsewhere; revert.
// gemm_o / gemm_xa / attn_v4 / prep = R16 verbatim.

#define BB 32
#define SS 257
#define DD 1024
#define HH 16
#define HDIM 64
#define EE 8
#define RR 16
#define MTOT (BB * SS)   // 8224
#define MPAD 8448        // 33 * 256
#define VTS 264          // vT t-stride (257 pad to 264)

typedef __attribute__((ext_vector_type(8))) _Float16 f16x8;
typedef __attribute__((ext_vector_type(4))) float f32x4;

static __device__ __forceinline__ float4 ld4(const float* p) {
    return *(const float4*)p;
}
static __device__ __forceinline__ unsigned short f16b(float x) {
    union { _Float16 f; unsigned short u; } cv;
    cv.f = (_Float16)x;
    return cv.u;
}

static __device__ __forceinline__ void gl_lds16(const unsigned short* g,
                                                unsigned short* l) {
    __builtin_amdgcn_global_load_lds(
        (const __attribute__((address_space(1))) unsigned int*)g,
        (__attribute__((address_space(3))) unsigned int*)l, 16, 0, 0);
}

// bijective XCD swizzle (m204)
static __device__ __forceinline__ int xcd_swz(int orig, int nwg) {
    const int xcd = orig & 7;
    const int lin = orig >> 3;
    const int q = nwg >> 3;
    const int r = nwg & 7;
    return (xcd < r ? xcd * (q + 1) : r * (q + 1) + (xcd - r) * q) + lin;
}

// ---------------------------------------------------------------------------
// prep (unchanged)
// ---------------------------------------------------------------------------
__global__ __launch_bounds__(256) void prep(
    const float* __restrict__ hidden, const float* __restrict__ wq,
    const float* __restrict__ wk, const float* __restrict__ wv,
    const float* __restrict__ wo, const float* __restrict__ Aq,
    const float* __restrict__ Ak, const float* __restrict__ Av,
    const float* __restrict__ Ao, const float* __restrict__ Bq,
    const float* __restrict__ Bk, const float* __restrict__ Bv,
    const float* __restrict__ Bo, const int* __restrict__ tki,
    const float* __restrict__ tkg, unsigned short* __restrict__ Xf,
    unsigned short* __restrict__ Wcat, unsigned short* __restrict__ Who,
    unsigned short* __restrict__ A3, unsigned short* __restrict__ Ao16,
    unsigned short* __restrict__ Bccat, unsigned short* __restrict__ Bco)
{
    const int tid = threadIdx.x;
    int bx = blockIdx.x;
    if (bx < 8448) { // X
        long i = ((long)bx * 256 + tid) * 4;
        float4 v = (i < (long)MTOT * DD) ? ld4(&hidden[i])
                                         : make_float4(0.f, 0.f, 0.f, 0.f);
        ushort4 hv;
        hv.x = f16b(v.x); hv.y = f16b(v.y); hv.z = f16b(v.z); hv.w = f16b(v.w);
        *(ushort4*)&Xf[i] = hv;
        return;
    }
    bx -= 8448;
    if (bx < 4096) { // W x4
        const int sel = bx >> 10;
        long i = ((long)(bx & 1023) * 256 + tid) * 4;
        const float* src = (sel == 0) ? wq : (sel == 1) ? wk
                                          : (sel == 2) ? wv : wo;
        unsigned short* dst =
            (sel < 3) ? Wcat + (size_t)sel * DD * DD : Who;
        float4 v = ld4(&src[i]);
        ushort4 hv;
        hv.x = f16b(v.x); hv.y = f16b(v.y); hv.z = f16b(v.z); hv.w = f16b(v.w);
        *(ushort4*)&dst[i] = hv;
        return;
    }
    bx -= 4096;
    if (bx < 512) { // A x4
        const int sel = bx >> 7;
        long i = ((long)(bx & 127) * 256 + tid) * 4;
        const float* src = (sel == 0) ? Aq : (sel == 1) ? Ak
                                          : (sel == 2) ? Av : Ao;
        unsigned short* dst =
            (sel < 3) ? A3 + (size_t)sel * EE * RR * DD : Ao16;
        float4 v = ld4(&src[i]);
        ushort4 hv;
        hv.x = f16b(v.x); hv.y = f16b(v.y); hv.z = f16b(v.z); hv.w = f16b(v.w);
        *(ushort4*)&dst[i] = hv;
        return;
    }
    bx -= 512;
    { // bcat x4
        const int set = bx >> 8;
        const int i = (bx & 255) * 256 + tid; // 0..65535
        const int b = i >> 11;
        const int rem = i & 2047;
        const int n = rem >> 1;
        const int ke = rem & 1;
        const float* Ball = (set == 0) ? Bq : (set == 1) ? Bk
                                           : (set == 2) ? Bv : Bo;
        const int e = tki[b * 2 + ke];
        const float g = tkg[b * 2 + ke];
        const float* sp = &Ball[((size_t)e * DD + n) * RR];
        unsigned short o16[16];
#pragma unroll
        for (int r4 = 0; r4 < 4; ++r4) {
            float4 v = ld4(sp + r4 * 4);
            o16[r4 * 4 + 0] = f16b(g * v.x);
            o16[r4 * 4 + 1] = f16b(g * v.y);
            o16[r4 * 4 + 2] = f16b(g * v.z);
            o16[r4 * 4 + 3] = f16b(g * v.w);
        }
        unsigned short* dst =
            (set < 3) ? &Bccat[((size_t)b * 3072 + set * 1024 + n) * 32 + ke * 16]
                      : &Bco[((size_t)b * 1024 + n) * 32 + ke * 16];
        *(uint4*)&dst[0] = *(uint4*)&o16[0];
        *(uint4*)&dst[8] = *(uint4*)&o16[8];
    }
}

// ---------------------------------------------------------------------------
// gemm_xa: XA[m][p*128+n] = Xf · Ap^T. 128x128 tile, single-sync 2-buf
// loop (stage k+1 overlaps compute k; 32 barriers). grid (npt, 65).
// ---------------------------------------------------------------------------
#define GSYNC() asm volatile("s_waitcnt vmcnt(0)\n\ts_barrier" ::: "memory")

#define XA_STAGE(BUFI, KT)                                                     \
    do {                                                                       \
        unsigned short* base_ = Sx + (BUFI) * 8192;                            \
        const int k0_ = (KT) * 32;                                             \
        gl_lds16(Xf + xr0 + k0_, base_ + lbase);                               \
        gl_lds16(Xf + xr1 + k0_, base_ + 2048 + lbase);                        \
        gl_lds16(Ap + ar0 + k0_, base_ + 4096 + lbase);                        \
        gl_lds16(Ap + ar1 + k0_, base_ + 6144 + lbase);                        \
    } while (0)

#define XA_COMPUTE(BUFI)                                                       \
    do {                                                                       \
        const unsigned short* Ab_ = Sx + (BUFI) * 8192;                        \
        const unsigned short* Bb_ = Ab_ + 4096;                                \
        f16x8 af[4], bf[4];                                                    \
        const int sb = (quad ^ ((l16 >> 1) & 3)) * 8;                          \
        _Pragma("unroll") for (int t = 0; t < 4; ++t) {                        \
            af[t] = *(const f16x8*)&Ab_[(wm + t * 16 + l16) * 32 + sb];        \
            bf[t] = *(const f16x8*)&Bb_[(wn + t * 16 + l16) * 32 + sb];        \
        }                                                                      \
        _Pragma("unroll") for (int i = 0; i < 4; ++i)                          \
        _Pragma("unroll") for (int j = 0; j < 4; ++j)                          \
            acc[i][j] = __builtin_amdgcn_mfma_f32_16x16x32_f16(                \
                af[i], bf[j], acc[i][j], 0, 0, 0);                             \
    } while (0)

__global__ __launch_bounds__(256) void gemm_xa(
    const unsigned short* __restrict__ Xf, const unsigned short* __restrict__ A0,
    const unsigned short* __restrict__ A1, const unsigned short* __restrict__ A2,
    unsigned short* __restrict__ XA, int ncols)
{
    // 2 buffers, each A[128][32] (4096 us) + B[128][32] (4096 us) = 16 KB.
    __shared__ unsigned short Sx[16384];
    const int tid = threadIdx.x;
    const int m0 = blockIdx.y * 128;
    const int p = blockIdx.x;
    const unsigned short* Ap = (p == 0) ? A0 : (p == 1) ? A1 : A2;
    const int lane = tid & 63;
    const int w = tid >> 6;
    const int wm = (w >> 1) * 64;
    const int wn = (w & 1) * 64;
    const int l16 = lane & 15;
    const int quad = lane >> 4;

    f32x4 acc[4][4];
#pragma unroll
    for (int i = 0; i < 4; ++i)
#pragma unroll
        for (int j = 0; j < 4; ++j) acc[i][j] = (f32x4){0.f, 0.f, 0.f, 0.f};

    const int srow = tid >> 2;
    const int scol = (((tid & 3) ^ ((tid >> 3) & 3))) * 8;
    const int lbase = (tid & 192) * 8;
    const size_t xr0 = (size_t)(m0 + srow) * DD + scol;
    const size_t xr1 = (size_t)(m0 + srow + 64) * DD + scol;
    const size_t ar0 = (size_t)srow * DD + scol;
    const size_t ar1 = (size_t)(srow + 64) * DD + scol;

    XA_STAGE(0, 0);
#pragma unroll 1
    for (int kt = 0; kt < 32; ++kt) {
        GSYNC();
        if (kt < 31) XA_STAGE((kt + 1) & 1, kt + 1);
        XA_COMPUTE(kt & 1);
    }

#pragma unroll
    for (int j = 0; j < 4; ++j) {
        const int col = p * 128 + wn + j * 16 + l16;
#pragma unroll
        for (int i = 0; i < 4; ++i) {
            const int mb = m0 + wm + i * 16 + quad * 4;
#pragma unroll
            for (int rg = 0; rg < 4; ++rg) {
                const int m = mb + rg;
                if (m < MTOT)
                    XA[(size_t)m * ncols + col] = f16b(acc[i][j][rg]);
            }
        }
    }
}

// ---------------------------------------------------------------------------
// Shared 256x128-tile / 8-wave pieces (R14-gemm_o-proven) used by gemm_qkv
// and gemm_o. Buffer i at S + i*12288 us: A[256][32] at +0, B[128][32] at
// +8192. Stage = 3 gl_lds16/thread (A rows w*32..+31, B rows w*16..+15).
// ---------------------------------------------------------------------------
#define T3_STAGE(BUFI, KT, BMAT)                                               \
    do {                                                                       \
        unsigned short* b_ = S + (BUFI) * 12288;                               \
        const int k0_ = (KT) * 32;                                             \
        gl_lds16(Xf + gA1 + k0_, b_ + w * 1024);                               \
        gl_lds16(Xf + gA2 + k0_, b_ + w * 1024 + 512);                         \
        gl_lds16(BMAT + gB + k0_, b_ + 8192 + w * 512);                        \
    } while (0)

#define T3_PHASES(BUFI)                                                        \
    do {                                                                       \
        const unsigned short* Ab_ = S + (BUFI) * 12288;                        \
        const unsigned short* Bb_ = Ab_ + 8192;                                \
        f16x8 af_[4], bf_[4];                                                  \
        _Pragma("unroll") for (int j = 0; j < 4; ++j)                          \
            bf_[j] = *(const f16x8*)&Bb_[boff + j * 512];                      \
        _Pragma("unroll") for (int i = 0; i < 4; ++i)                          \
            af_[i] = *(const f16x8*)&Ab_[aoff + i * 512];                      \
        __builtin_amdgcn_s_setprio(1);                                         \
        _Pragma("unroll") for (int i = 0; i < 4; ++i)                          \
        _Pragma("unroll") for (int j = 0; j < 4; ++j)                          \
            acc[i][j] = __builtin_amdgcn_mfma_f32_16x16x32_f16(                \
                af_[i], bf_[j], acc[i][j], 0, 0, 0);                           \
        __builtin_amdgcn_s_setprio(0);                                         \
    } while (0)

// ---------------------------------------------------------------------------
// gemm_qkv: 256x128 tile, 512 thr / 8 waves (4Mx2N of 64x64), 2x24KB LDS
// (48KB -> 3 blocks/CU). grid 792 = 33m x 24n (XCD-swizzled, m-major).
// ---------------------------------------------------------------------------
__global__ __launch_bounds__(512)
__attribute__((amdgpu_waves_per_eu(2, 8))) void gemm_qkv(
    const unsigned short* __restrict__ Xf, const unsigned short* __restrict__ Wcat,
    const float* __restrict__ bq, const float* __restrict__ bk,
    const float* __restrict__ bv, const unsigned short* __restrict__ XAd,
    const unsigned short* __restrict__ Bccat, const int* __restrict__ idx,
    unsigned short* __restrict__ qh, unsigned short* __restrict__ kh,
    unsigned short* __restrict__ vTg)
{
    __shared__ unsigned short S[24576];  // 2 x 24 KB buffers
    const int tid = threadIdx.x;
    const int wgid = xcd_swz(blockIdx.x, 792);
    const int bxn = wgid % 24;           // 0..23
    const int m0 = (wgid / 24) * 256;    // 33 m-tiles
    const int p = bxn >> 3;              // projection 0=q 1=k 2=v
    const int n0g = bxn * 128;           // global col in Wcat
    const int nloc0 = (bxn & 7) * 128;   // col within the projection's 1024
    const int lane = tid & 63;
    const int w = tid >> 6;              // wave 0..7
    const int wm = (w >> 1) * 64;        // 0..192 (M)
    const int wn = (w & 1) * 64;         // 0/64 (N)
    const int l16 = lane & 15;
    const int quad = lane >> 4;
    const int sb = (quad ^ ((l16 >> 1) & 3)) * 8;
    const int aoff = (wm + l16) * 32 + sb;
    const int boff = (wn + l16) * 32 + sb;

    f32x4 acc[4][4];
#pragma unroll
    for (int i = 0; i < 4; ++i)
#pragma unroll
        for (int j = 0; j < 4; ++j) acc[i][j] = (f32x4){0.f, 0.f, 0.f, 0.f};

    // staging addresses (XOR chunk swizzle; key invariant under +16 rows)
    const int rowA1 = w * 32 + (lane >> 2);          // 0..255 (first half)
    const int chk = lane & 3;
    const int keyA = (rowA1 >> 1) & 3;
    const size_t gA1 = (size_t)(m0 + rowA1) * DD + (chk ^ keyA) * 8;
    const size_t gA2 = gA1 + (size_t)16 * DD;        // rowA1+16, same key
    const int rowB = w * 16 + (lane >> 2);           // 0..127
    const int keyB = (rowB >> 1) & 3;
    const size_t gB = (size_t)(n0g + rowB) * DD + (chk ^ keyB) * 8;

    // ---- main K loop: 2-buf double buffer ----
    T3_STAGE(0, 0, Wcat);
#pragma unroll 1
    for (int kt = 0; kt < 32; ++kt) {
        GSYNC();
        if (kt < 31) T3_STAGE((kt + 1) & 1, kt + 1, Wcat);
        T3_PHASES(kt & 1);
    }

    // ---- LoRA tail (k=32: 2 experts x 16 r) into buffer 0 ----
    {
        int m_hi = m0 + 255;
        if (m_hi >= MTOT) m_hi = MTOT - 1;
        const int b_first = m0 / SS;
        const int b_last = m_hi / SS;
        const int rA = tid >> 1;         // 0..255
        const int b0 = (tid & 1) * 2;
        const int keyTA = (rA >> 1) & 3;
        const int g0 = b0 ^ keyTA, g1 = (b0 + 1) ^ keyTA;
        const int rB = tid >> 2;         // 0..127
        const int ccB = tid & 3;
        const int gBt = ccB ^ ((rB >> 1) & 3);
        const uint4 z = make_uint4(0, 0, 0, 0);
#pragma unroll 1
        for (int bp = b_first; bp <= b_last; ++bp) {
            const int gm = m0 + rA;
            const bool va = (gm < MTOT) && (gm / SS == bp);
            uint4 av0 = z, av1 = z;
            if (va) {
                const int e0 = idx[bp * 2 + (g0 >> 1)];
                const int e1 = idx[bp * 2 + (g1 >> 1)];
                av0 = *(const uint4*)&XAd[(size_t)gm * 384 + p * 128 +
                                          e0 * 16 + (g0 & 1) * 8];
                av1 = *(const uint4*)&XAd[(size_t)gm * 384 + p * 128 +
                                          e1 * 16 + (g1 & 1) * 8];
            }
            const size_t bo = ((size_t)bp * 3072 + p * 1024 + nloc0 + rB) * 32;
            uint4 bv2 = *(const uint4*)&Bccat[bo + gBt * 8];
            __syncthreads();
            *(uint4*)&S[rA * 32 + b0 * 8] = av0;
            *(uint4*)&S[rA * 32 + (b0 + 1) * 8] = av1;
            *(uint4*)&S[8192 + rB * 32 + ccB * 8] = bv2;
            __syncthreads();
            T3_PHASES(0);
            __syncthreads();
        }
    }

    // ---- epilogue (reuses S; 48KB budget; static acc indices) ----
    unsigned short* Epi = S;
    const float* bias = (p == 0) ? bq : (p == 1) ? bk : bv;
    if (p < 2) {
        // q/k: 2 half passes of 128 rows through Epi[128][136] (34.8KB)
        const float alpha = (p == 0) ? 0.125f : 1.0f;
        unsigned short* C = (p == 0) ? qh : kh;
#pragma unroll 1
        for (int half = 0; half < 2; ++half) {
            if ((w >> 2) == half) {      // waves 4h..4h+3 own rows h*128..+127
                const int lm0 = wm - half * 128;   // 0 or 64
#pragma unroll
                for (int j = 0; j < 4; ++j) {
                    const int col = wn + j * 16 + l16;
                    const float bvl = bias[nloc0 + col];
#pragma unroll
                    for (int i = 0; i < 4; ++i) {
                        const int ml = lm0 + i * 16 + quad * 4; // 0..127
#pragma unroll
                        for (int rg = 0; rg < 4; ++rg)
                            Epi[(ml + rg) * 136 + col] =
                                f16b(alpha * (acc[i][j][rg] + bvl));
                    }
                }
            }
            __syncthreads();
            {
                const int r = tid >> 2;          // 0..127
                const int c = (tid & 3) * 32;    // 0..96
                const int m = m0 + half * 128 + r;
                if (m < MTOT) {
#pragma unroll
                    for (int k = 0; k < 4; ++k)
                        *(uint4*)&C[(size_t)m * DD + nloc0 + c + k * 8] =
                            *(const uint4*)&Epi[r * 136 + c + k * 8];
                }
            }
            __syncthreads();
        }
    } else {
        // v: transposed -> vT[(b*16+h)*64+d][t]; Epi[128][68] (17.4KB)
#pragma unroll 1
        for (int hh = 0; hh < 4; ++hh) {
            if ((w >> 1) == hh) {        // waves 2hh,2hh+1 own rows hh*64..+63
#pragma unroll
                for (int j = 0; j < 4; ++j) {
                    const int col = wn + j * 16 + l16;   // 0..127
                    const float bvl = bias[nloc0 + col];
#pragma unroll
                    for (int i = 0; i < 4; ++i) {
                        const int ml = i * 16 + quad * 4;  // 0..63
                        ushort4 pk;
                        pk.x = f16b(acc[i][j][0] + bvl);
                        pk.y = f16b(acc[i][j][1] + bvl);
                        pk.z = f16b(acc[i][j][2] + bvl);
                        pk.w = f16b(acc[i][j][3] + bvl);
                        *(ushort4*)&Epi[col * 68 + ml] = pk;
                    }
                }
            }
            __syncthreads();
            {
                const int tl = tid & 63;
                const int mg = m0 + hh * 64 + tl;
                if (mg < MTOT) {
                    const int bq2 = mg / SS;
                    const int t = mg - bq2 * SS;
#pragma unroll 4
                    for (int k = 0; k < 16; ++k) {
                        const int nll = (tid >> 6) + k * 8;   // 0..127
                        const int d = nloc0 + nll;            // 0..1023
                        vTg[((size_t)(bq2 * HH + (d >> 6)) * HDIM + (d & 63)) *
                                VTS + t] = Epi[nll * 68 + tl];
                    }
                }
            }
            __syncthreads();
        }
    }
}

// ---------------------------------------------------------------------------
// gemm_o: 256x128 tile, 512 thr / 8 waves, 2x24KB LDS. grid 264
// (XCD-swizzled, m-major); fp32 out. (R16 verbatim, shared macros.)
// ---------------------------------------------------------------------------
__global__ __launch_bounds__(512)
__attribute__((amdgpu_waves_per_eu(2, 8))) void gemm_o(
    const unsigned short* __restrict__ Xf, const unsigned short* __restrict__ Wh2,
    const float* __restrict__ bias, const unsigned short* __restrict__ XAo,
    const unsigned short* __restrict__ Bco, const int* __restrict__ idx,
    float* __restrict__ Cf)
{
    __shared__ unsigned short S[24576];
    const int tid = threadIdx.x;
    const int wgid = xcd_swz(blockIdx.x, 264);
    const int m0 = (wgid >> 3) * 256;    // 33 m-tiles
    const int n0 = (wgid & 7) * 128;     // 8 n-tiles
    const int lane = tid & 63;
    const int w = tid >> 6;              // wave 0..7
    const int wm = (w >> 1) * 64;        // 0..192
    const int wn = (w & 1) * 64;         // 0..64
    const int l16 = lane & 15;
    const int quad = lane >> 4;
    const int sb = (quad ^ ((l16 >> 1) & 3)) * 8;
    const int aoff = (wm + l16) * 32 + sb;
    const int boff = (wn + l16) * 32 + sb;

    f32x4 acc[4][4];
#pragma unroll
    for (int i = 0; i < 4; ++i)
#pragma unroll
        for (int j = 0; j < 4; ++j) acc[i][j] = (f32x4){0.f, 0.f, 0.f, 0.f};

    const int rowA1 = w * 32 + (lane >> 2);          // 0..255 (first half)
    const int chk = lane & 3;
    const int keyA = (rowA1 >> 1) & 3;
    const size_t gA1 = (size_t)(m0 + rowA1) * DD + (chk ^ keyA) * 8;
    const size_t gA2 = gA1 + (size_t)16 * DD;        // rowA1+16, same key
    const int rowB = w * 16 + (lane >> 2);           // 0..127
    const int keyB = (rowB >> 1) & 3;
    const size_t gB = (size_t)(n0 + rowB) * DD + (chk ^ keyB) * 8;

    T3_STAGE(0, 0, Wh2);
#pragma unroll 1
    for (int kt = 0; kt < 32; ++kt) {
        GSYNC();
        if (kt < 31) T3_STAGE((kt + 1) & 1, kt + 1, Wh2);
        T3_PHASES(kt & 1);
    }

    // ---- LoRA tail ----
    {
        int m_hi = m0 + 255;
        if (m_hi >= MTOT) m_hi = MTOT - 1;
        const int b_first = m0 / SS;
        const int b_last = m_hi / SS;
        const int rA = tid >> 1;         // 0..255
        const int b0 = (tid & 1) * 2;
        const int keyTA = (rA >> 1) & 3;
        const int g0 = b0 ^ keyTA, g1 = (b0 + 1) ^ keyTA;
        const int rB = tid >> 2;         // 0..127
        const int ccB = tid & 3;
        const int gBt = ccB ^ ((rB >> 1) & 3);
        const uint4 z = make_uint4(0, 0, 0, 0);
#pragma unroll 1
        for (int bp = b_first; bp <= b_last; ++bp) {
            const int gm = m0 + rA;
            const bool va = (gm < MTOT) && (gm / SS == bp);
            uint4 av0 = z, av1 = z;
            if (va) {
                const int e0 = idx[bp * 2 + (g0 >> 1)];
                const int e1 = idx[bp * 2 + (g1 >> 1)];
                av0 = *(const uint4*)&XAo[(size_t)gm * 128 + e0 * 16 +
                                          (g0 & 1) * 8];
                av1 = *(const uint4*)&XAo[(size_t)gm * 128 + e1 * 16 +
                                          (g1 & 1) * 8];
            }
            const size_t bo = ((size_t)bp * 1024 + n0 + rB) * 32;
            uint4 bv2 = *(const uint4*)&Bco[bo + gBt * 8];
            __syncthreads();
            *(uint4*)&S[rA * 32 + b0 * 8] = av0;
            *(uint4*)&S[rA * 32 + (b0 + 1) * 8] = av1;
            *(uint4*)&S[8192 + rB * 32 + ccB * 8] = bv2;
            __syncthreads();
            T3_PHASES(0);
            __syncthreads();
        }
    }

#pragma unroll
    for (int j = 0; j < 4; ++j) {
        const int n = n0 + wn + j * 16 + l16;
        const float bvl = bias[n];
#pragma unroll
        for (int i = 0; i < 4; ++i) {
            const int mb = m0 + wm + i * 16 + quad * 4;
#pragma unroll
            for (int rg = 0; rg < 4; ++rg) {
                const int m = mb + rg;
                if (m < MTOT) Cf[(size_t)m * DD + n] = acc[i][j][rg] + bvl;
            }
        }
    }
}

// ---------------------------------------------------------------------------
// attn_v4 (unchanged)
// ---------------------------------------------------------------------------
__global__ __launch_bounds__(512, 1) void attn_v4(
    const unsigned short* __restrict__ qh, const unsigned short* __restrict__ kh,
    const unsigned short* __restrict__ vT, unsigned short* __restrict__ Xf)
{
    __shared__ unsigned short Ks[288 * 64];
    __shared__ unsigned short Vt[64 * VTS];
    __shared__ unsigned short Qs[64 * 64];
    __shared__ unsigned short Ps[64 * 296];
    __shared__ float sredm[2][64];
    __shared__ float sreds[2][64];

    const int tid = threadIdx.x;
    const int h = blockIdx.x, b = blockIdx.y;
    const int cb = h * HDIM;
    const int lane = tid & 63;
    const int w = tid >> 6;
    const int r0 = (w & 3) * 16;
    const int ch = w >> 2;
    const int l16 = lane & 15;
    const int quad = lane >> 4;

    const size_t kbase = (size_t)(b * SS) * DD + cb;
    {
        const int rr = w * 8 + (lane >> 3);
        const int cg = ((lane & 7) ^ (rr & 7)) * 8;
#pragma unroll
        for (int c = 0; c < 4; ++c)
            gl_lds16(kh + kbase + (size_t)(c * 64 + rr) * DD + cg,
                     &Ks[(c * 64 + w * 8) * 64]);
    }
    if (tid < 256) {
        uint4 z = make_uint4(0, 0, 0, 0);
        if (tid < 8) z = *(const uint4*)&kh[kbase + (size_t)256 * DD + tid * 8];
        *(uint4*)&Ks[256 * 64 + tid * 8] = z;
    }
    {
        const size_t vbase = (size_t)(b * HH + h) * HDIM * VTS;
        for (int i = tid; i < 64 * 33; i += 512) {
            const int r = i / 33;
            const int c = i - r * 33;
            uint4 v = *(const uint4*)&vT[vbase + (size_t)r * VTS + c * 8];
            if (c == 32) { v.x &= 0xFFFFu; v.y = 0; v.z = 0; v.w = 0; }
            *(uint4*)&Vt[r * VTS + c * 8] = v;
        }
    }

#pragma unroll 1
    for (int qt = 0; qt < 5; ++qt) {
        const int s0 = qt * 64;
        __syncthreads();
        {
            int sg = s0 + (tid >> 3);
            if (sg > SS - 1) sg = SS - 1;
            const int cg = ((tid & 7) ^ ((tid >> 3) & 7)) * 8;
            gl_lds16(qh + (size_t)(b * SS + sg) * DD + cb + cg,
                     &Qs[(w * 8) * 64]);
        }
        __syncthreads();

        f32x4 lac[9];
#pragma unroll
        for (int ct = 0; ct < 9; ++ct) lac[ct] = (f32x4){0.f, 0.f, 0.f, 0.f};
#pragma unroll
        for (int kc = 0; kc < 2; ++kc) {
            const int sb = ((kc * 4 + quad) ^ (l16 & 7)) * 8;
            f16x8 af = *(const f16x8*)&Qs[(r0 + l16) * 64 + sb];
#pragma unroll
            for (int ct = 0; ct < 9; ++ct) {
                const int c0 = ch * 144 + ct * 16;
                f16x8 bf = *(const f16x8*)&Ks[(c0 + l16) * 64 + sb];
                lac[ct] = __builtin_amdgcn_mfma_f32_16x16x32_f16(
                    af, bf, lac[ct], 0, 0, 0);
            }
        }
#pragma unroll
        for (int ct = 0; ct < 9; ++ct) {
            const int t = ch * 144 + ct * 16 + l16;
            if (t > SS - 1) {
                lac[ct][0] = -1e30f; lac[ct][1] = -1e30f;
                lac[ct][2] = -1e30f; lac[ct][3] = -1e30f;
            }
        }
        float mx[4] = {-1e30f, -1e30f, -1e30f, -1e30f};
#pragma unroll
        for (int ct = 0; ct < 9; ++ct)
#pragma unroll
            for (int i = 0; i < 4; ++i) mx[i] = fmaxf(mx[i], lac[ct][i]);
#pragma unroll
        for (int o = 1; o < 16; o <<= 1)
#pragma unroll
            for (int i = 0; i < 4; ++i)
                mx[i] = fmaxf(mx[i], __shfl_xor(mx[i], o, 16));
        if (l16 == 0)
#pragma unroll
            for (int i = 0; i < 4; ++i) sredm[ch][r0 + quad * 4 + i] = mx[i];
        __syncthreads();
#pragma unroll
        for (int i = 0; i < 4; ++i)
            mx[i] = fmaxf(mx[i], sredm[1 - ch][r0 + quad * 4 + i]);
        float sm[4] = {0.f, 0.f, 0.f, 0.f};
#pragma unroll
        for (int ct = 0; ct < 9; ++ct)
#pragma unroll
            for (int i = 0; i < 4; ++i) {
                float pv = __expf(lac[ct][i] - mx[i]);
                lac[ct][i] = pv;
                sm[i] += pv;
            }
#pragma unroll
        for (int o = 1; o < 16; o <<= 1)
#pragma unroll
            for (int i = 0; i < 4; ++i) sm[i] += __shfl_xor(sm[i], o, 16);
        if (l16 == 0)
#pragma unroll
            for (int i = 0; i < 4; ++i) sreds[ch][r0 + quad * 4 + i] = sm[i];
        __syncthreads();
        float inv[4];
#pragma unroll
        for (int i = 0; i < 4; ++i)
            inv[i] = 1.f / (sm[i] + sreds[1 - ch][r0 + quad * 4 + i]);
#pragma unroll
        for (int ct = 0; ct < 9; ++ct) {
            const int col = ch * 144 + ct * 16 + l16;
#pragma unroll
            for (int i = 0; i < 4; ++i)
                Ps[(r0 + quad * 4 + i) * 296 + col] =
                    f16b(lac[ct][i] * inv[i]);
        }
        __syncthreads();

        f32x4 oacc[2];
        oacc[0] = (f32x4){0.f, 0.f, 0.f, 0.f};
        oacc[1] = (f32x4){0.f, 0.f, 0.f, 0.f};
#pragma unroll
        for (int tt = 0; tt < 9; ++tt) {
            const int t0 = tt * 32;
            f16x8 pf = *(const f16x8*)&Ps[(r0 + l16) * 296 + t0 + quad * 8];
#pragma unroll
            for (int dt = 0; dt < 2; ++dt) {
                f16x8 bvv = *(const f16x8*)&Vt[(ch * 32 + dt * 16 + l16) * VTS +
                                               t0 + quad * 8];
                oacc[dt] = __builtin_amdgcn_mfma_f32_16x16x32_f16(
                    pf, bvv, oacc[dt], 0, 0, 0);
            }
        }
#pragma unroll
        for (int dt = 0; dt < 2; ++dt)
#pragma unroll
            for (int i = 0; i < 4; ++i) {
                const int srow = s0 + r0 + quad * 4 + i;
                if (srow < SS)
                    Xf[(size_t)(b * SS + srow) * DD + cb + ch * 32 + dt * 16 +
                       l16] = f16b(oacc[dt][i]);
            }
    }
}

// ---------------------------------------------------------------------------
extern "C" void kernel_launch(void* const* d_in, const int* in_sizes, int n_in,
                              void* d_out, int out_size, void* d_ws,
                              size_t ws_size, hipStream_t stream)
{
    const float* hidden = (const float*)d_in[0];
    const int* tki = (const int*)d_in[1];
    const float* tkg = (const float*)d_in[2];
    const float* wq = (const float*)d_in[3];
    const float* Aq = (const float*)d_in[4];
    const float* Bq = (const float*)d_in[5];
    const float* bq = (const float*)d_in[6];
    const float* wk = (const float*)d_in[7];
    const float* Ak = (const float*)d_in[8];
    const float* Bk = (const float*)d_in[9];
    const float* bkb = (const float*)d_in[10];
    const float* wv = (const float*)d_in[11];
    const float* Av = (const float*)d_in[12];
    const float* Bv = (const float*)d_in[13];
    const float* bvb = (const float*)d_in[14];
    const float* wo = (const float*)d_in[15];
    const float* Ao = (const float*)d_in[16];
    const float* Bo = (const float*)d_in[17];
    const float* bob = (const float*)d_in[18];
    float* out = (float*)d_out;

    // ---- workspace (~72 MB) ----
    char* ws = (char*)d_ws;
    const size_t NW = (size_t)DD * DD;
    const size_t NA = (size_t)EE * RR * DD;
    unsigned short* Xf = (unsigned short*)ws;    ws += (size_t)MPAD * DD * 2;
    unsigned short* qh = (unsigned short*)ws;    ws += (size_t)MTOT * DD * 2;
    unsigned short* vTg = (unsigned short*)ws;   ws += (size_t)BB * HH * HDIM * VTS * 2;
    unsigned short* Wcat = (unsigned short*)ws;  ws += 3 * NW * 2;
    unsigned short* Who = (unsigned short*)ws;   ws += NW * 2;
    unsigned short* A3 = (unsigned short*)ws;    ws += 3 * NA * 2;
    unsigned short* Ao16 = (unsigned short*)ws;  ws += NA * 2;
    unsigned short* Bccat = (unsigned short*)ws; ws += (size_t)BB * 3072 * 32 * 2;
    unsigned short* Bco = (unsigned short*)ws;   ws += (size_t)BB * 1024 * 32 * 2;
    unsigned short* XAo = (unsigned short*)ws;   ws += (size_t)MTOT * 128 * 2;
    // parked in d_out (dead before gemm_o writes out):
    unsigned short* kh = (unsigned short*)d_out;
    unsigned short* XAd = (unsigned short*)((char*)d_out + (size_t)MTOT * DD * 2);

    prep<<<14080, 256, 0, stream>>>(hidden, wq, wk, wv, wo, Aq, Ak, Av, Ao,
                                    Bq, Bk, Bv, Bo, tki, tkg, Xf, Wcat, Who,
                                    A3, Ao16, Bccat, Bco);
    gemm_xa<<<dim3(3, 65), 256, 0, stream>>>(Xf, A3, A3 + NA, A3 + 2 * NA,
                                             XAd, 384);
    gemm_qkv<<<792, 512, 0, stream>>>(Xf, Wcat, bq, bkb, bvb, XAd,
                                      Bccat, tki, qh, kh, vTg);
    attn_v4<<<dim3(HH, BB), 512, 0, stream>>>(qh, kh, vTg, Xf);
    gemm_xa<<<dim3(1, 65), 256, 0, stream>>>(Xf, Ao16, Ao16, Ao16, XAo, 128);
    gemm_o<<<264, 512, 0, stream>>>(Xf, Who, bob, XAo, Bco, tki, out);
}

// Round 13
// 320.803 us; speedup vs baseline: 1.1187x; 1.1187x over previous
//
#include <hip/hip_runtime.h>

// ViTMoEAttention: B=32,S=257,D=1024,H=16,HD=64,E=8,R=16,K=2
// Round 20 = Round 16 (best verified: 324.78us), resubmitted after an
// infrastructure failure in Round 19 ("MI355X container failed twice" --
// the kernel never ran; no code-level evidence to update on).
//  - State: gemm_qkv = 2-buf 64KB / 16 waves / grid 396 (83us, frozen after
//    5 losing variants); gemm_xa = single-sync 2-buf; gemm_o = 256x128 /
//    8 waves / 48KB / grid 264; attn_v4 = original staged version (117KB
//    LDS); prep unchanged.

#define BB 32
#define SS 257
#define DD 1024
#define HH 16
#define HDIM 64
#define EE 8
#define RR 16
#define MTOT (BB * SS)   // 8224
#define MPAD 8448        // 33 * 256
#define VTS 264          // vT t-stride (257 pad to 264)

typedef __attribute__((ext_vector_type(8))) _Float16 f16x8;
typedef __attribute__((ext_vector_type(4))) float f32x4;

static __device__ __forceinline__ float4 ld4(const float* p) {
    return *(const float4*)p;
}
static __device__ __forceinline__ unsigned short f16b(float x) {
    union { _Float16 f; unsigned short u; } cv;
    cv.f = (_Float16)x;
    return cv.u;
}

static __device__ __forceinline__ void gl_lds16(const unsigned short* g,
                                                unsigned short* l) {
    __builtin_amdgcn_global_load_lds(
        (const __attribute__((address_space(1))) unsigned int*)g,
        (__attribute__((address_space(3))) unsigned int*)l, 16, 0, 0);
}

// bijective XCD swizzle (m204)
static __device__ __forceinline__ int xcd_swz(int orig, int nwg) {
    const int xcd = orig & 7;
    const int lin = orig >> 3;
    const int q = nwg >> 3;
    const int r = nwg & 7;
    return (xcd < r ? xcd * (q + 1) : r * (q + 1) + (xcd - r) * q) + lin;
}

// ---------------------------------------------------------------------------
// prep (unchanged)
// ---------------------------------------------------------------------------
__global__ __launch_bounds__(256) void prep(
    const float* __restrict__ hidden, const float* __restrict__ wq,
    const float* __restrict__ wk, const float* __restrict__ wv,
    const float* __restrict__ wo, const float* __restrict__ Aq,
    const float* __restrict__ Ak, const float* __restrict__ Av,
    const float* __restrict__ Ao, const float* __restrict__ Bq,
    const float* __restrict__ Bk, const float* __restrict__ Bv,
    const float* __restrict__ Bo, const int* __restrict__ tki,
    const float* __restrict__ tkg, unsigned short* __restrict__ Xf,
    unsigned short* __restrict__ Wcat, unsigned short* __restrict__ Who,
    unsigned short* __restrict__ A3, unsigned short* __restrict__ Ao16,
    unsigned short* __restrict__ Bccat, unsigned short* __restrict__ Bco)
{
    const int tid = threadIdx.x;
    int bx = blockIdx.x;
    if (bx < 8448) { // X
        long i = ((long)bx * 256 + tid) * 4;
        float4 v = (i < (long)MTOT * DD) ? ld4(&hidden[i])
                                         : make_float4(0.f, 0.f, 0.f, 0.f);
        ushort4 hv;
        hv.x = f16b(v.x); hv.y = f16b(v.y); hv.z = f16b(v.z); hv.w = f16b(v.w);
        *(ushort4*)&Xf[i] = hv;
        return;
    }
    bx -= 8448;
    if (bx < 4096) { // W x4
        const int sel = bx >> 10;
        long i = ((long)(bx & 1023) * 256 + tid) * 4;
        const float* src = (sel == 0) ? wq : (sel == 1) ? wk
                                          : (sel == 2) ? wv : wo;
        unsigned short* dst =
            (sel < 3) ? Wcat + (size_t)sel * DD * DD : Who;
        float4 v = ld4(&src[i]);
        ushort4 hv;
        hv.x = f16b(v.x); hv.y = f16b(v.y); hv.z = f16b(v.z); hv.w = f16b(v.w);
        *(ushort4*)&dst[i] = hv;
        return;
    }
    bx -= 4096;
    if (bx < 512) { // A x4
        const int sel = bx >> 7;
        long i = ((long)(bx & 127) * 256 + tid) * 4;
        const float* src = (sel == 0) ? Aq : (sel == 1) ? Ak
                                          : (sel == 2) ? Av : Ao;
        unsigned short* dst =
            (sel < 3) ? A3 + (size_t)sel * EE * RR * DD : Ao16;
        float4 v = ld4(&src[i]);
        ushort4 hv;
        hv.x = f16b(v.x); hv.y = f16b(v.y); hv.z = f16b(v.z); hv.w = f16b(v.w);
        *(ushort4*)&dst[i] = hv;
        return;
    }
    bx -= 512;
    { // bcat x4
        const int set = bx >> 8;
        const int i = (bx & 255) * 256 + tid; // 0..65535
        const int b = i >> 11;
        const int rem = i & 2047;
        const int n = rem >> 1;
        const int ke = rem & 1;
        const float* Ball = (set == 0) ? Bq : (set == 1) ? Bk
                                           : (set == 2) ? Bv : Bo;
        const int e = tki[b * 2 + ke];
        const float g = tkg[b * 2 + ke];
        const float* sp = &Ball[((size_t)e * DD + n) * RR];
        unsigned short o16[16];
#pragma unroll
        for (int r4 = 0; r4 < 4; ++r4) {
            float4 v = ld4(sp + r4 * 4);
            o16[r4 * 4 + 0] = f16b(g * v.x);
            o16[r4 * 4 + 1] = f16b(g * v.y);
            o16[r4 * 4 + 2] = f16b(g * v.z);
            o16[r4 * 4 + 3] = f16b(g * v.w);
        }
        unsigned short* dst =
            (set < 3) ? &Bccat[((size_t)b * 3072 + set * 1024 + n) * 32 + ke * 16]
                      : &Bco[((size_t)b * 1024 + n) * 32 + ke * 16];
        *(uint4*)&dst[0] = *(uint4*)&o16[0];
        *(uint4*)&dst[8] = *(uint4*)&o16[8];
    }
}

// ---------------------------------------------------------------------------
// gemm_xa: XA[m][p*128+n] = Xf · Ap^T. 128x128 tile, single-sync 2-buf
// loop (stage k+1 overlaps compute k; 32 barriers). grid (npt, 65).
// ---------------------------------------------------------------------------
#define GSYNC() asm volatile("s_waitcnt vmcnt(0)\n\ts_barrier" ::: "memory")

#define XA_STAGE(BUFI, KT)                                                     \
    do {                                                                       \
        unsigned short* base_ = Sx + (BUFI) * 8192;                            \
        const int k0_ = (KT) * 32;                                             \
        gl_lds16(Xf + xr0 + k0_, base_ + lbase);                               \
        gl_lds16(Xf + xr1 + k0_, base_ + 2048 + lbase);                        \
        gl_lds16(Ap + ar0 + k0_, base_ + 4096 + lbase);                        \
        gl_lds16(Ap + ar1 + k0_, base_ + 6144 + lbase);                        \
    } while (0)

#define XA_COMPUTE(BUFI)                                                       \
    do {                                                                       \
        const unsigned short* Ab_ = Sx + (BUFI) * 8192;                        \
        const unsigned short* Bb_ = Ab_ + 4096;                                \
        f16x8 af[4], bf[4];                                                    \
        const int sb = (quad ^ ((l16 >> 1) & 3)) * 8;                          \
        _Pragma("unroll") for (int t = 0; t < 4; ++t) {                        \
            af[t] = *(const f16x8*)&Ab_[(wm + t * 16 + l16) * 32 + sb];        \
            bf[t] = *(const f16x8*)&Bb_[(wn + t * 16 + l16) * 32 + sb];        \
        }                                                                      \
        _Pragma("unroll") for (int i = 0; i < 4; ++i)                          \
        _Pragma("unroll") for (int j = 0; j < 4; ++j)                          \
            acc[i][j] = __builtin_amdgcn_mfma_f32_16x16x32_f16(                \
                af[i], bf[j], acc[i][j], 0, 0, 0);                             \
    } while (0)

__global__ __launch_bounds__(256) void gemm_xa(
    const unsigned short* __restrict__ Xf, const unsigned short* __restrict__ A0,
    const unsigned short* __restrict__ A1, const unsigned short* __restrict__ A2,
    unsigned short* __restrict__ XA, int ncols)
{
    // 2 buffers, each A[128][32] (4096 us) + B[128][32] (4096 us) = 16 KB.
    __shared__ unsigned short Sx[16384];
    const int tid = threadIdx.x;
    const int m0 = blockIdx.y * 128;
    const int p = blockIdx.x;
    const unsigned short* Ap = (p == 0) ? A0 : (p == 1) ? A1 : A2;
    const int lane = tid & 63;
    const int w = tid >> 6;
    const int wm = (w >> 1) * 64;
    const int wn = (w & 1) * 64;
    const int l16 = lane & 15;
    const int quad = lane >> 4;

    f32x4 acc[4][4];
#pragma unroll
    for (int i = 0; i < 4; ++i)
#pragma unroll
        for (int j = 0; j < 4; ++j) acc[i][j] = (f32x4){0.f, 0.f, 0.f, 0.f};

    const int srow = tid >> 2;
    const int scol = (((tid & 3) ^ ((tid >> 3) & 3))) * 8;
    const int lbase = (tid & 192) * 8;
    const size_t xr0 = (size_t)(m0 + srow) * DD + scol;
    const size_t xr1 = (size_t)(m0 + srow + 64) * DD + scol;
    const size_t ar0 = (size_t)srow * DD + scol;
    const size_t ar1 = (size_t)(srow + 64) * DD + scol;

    XA_STAGE(0, 0);
#pragma unroll 1
    for (int kt = 0; kt < 32; ++kt) {
        GSYNC();
        if (kt < 31) XA_STAGE((kt + 1) & 1, kt + 1);
        XA_COMPUTE(kt & 1);
    }

#pragma unroll
    for (int j = 0; j < 4; ++j) {
        const int col = p * 128 + wn + j * 16 + l16;
#pragma unroll
        for (int i = 0; i < 4; ++i) {
            const int mb = m0 + wm + i * 16 + quad * 4;
#pragma unroll
            for (int rg = 0; rg < 4; ++rg) {
                const int m = mb + rg;
                if (m < MTOT)
                    XA[(size_t)m * ncols + col] = f16b(acc[i][j][rg]);
            }
        }
    }
}

// ---------------------------------------------------------------------------
// Shared 256-row-tile / 16-wave pieces for gemm_qkv (2 x 32KB buffers).
// (R13/R16-proven configuration.)
// ---------------------------------------------------------------------------
#define QKV_STAGE(BUFI, KT)                                                    \
    do {                                                                       \
        unsigned short* dA_ = S + (BUFI) * 16384 + w * 512;                    \
        const int k0_ = (KT) * 32;                                             \
        gl_lds16(Xf + gA + k0_, dA_);                                          \
        gl_lds16(Wcat + gB + k0_, dA_ + 8192);                                 \
    } while (0)

#define QKV_PHASES(BUFI)                                                       \
    do {                                                                       \
        const unsigned short* Ab_ = S + (BUFI) * 16384;                        \
        const unsigned short* Bb_ = Ab_ + 8192;                                \
        f16x8 af_[4], bf_[4];                                                  \
        _Pragma("unroll") for (int j = 0; j < 4; ++j)                          \
            bf_[j] = *(const f16x8*)&Bb_[boff + j * 512];                      \
        _Pragma("unroll") for (int i = 0; i < 4; ++i)                          \
            af_[i] = *(const f16x8*)&Ab_[aoff + i * 512];                      \
        __builtin_amdgcn_s_setprio(1);                                         \
        _Pragma("unroll") for (int i = 0; i < 4; ++i)                          \
        _Pragma("unroll") for (int j = 0; j < 4; ++j)                          \
            acc[i][j] = __builtin_amdgcn_mfma_f32_16x16x32_f16(                \
                af_[i], bf_[j], acc[i][j], 0, 0, 0);                           \
        __builtin_amdgcn_s_setprio(0);                                         \
    } while (0)

// ---------------------------------------------------------------------------
// gemm_qkv: 64KB LDS (2 buffers), stage-ahead double buffer (R16-proven).
// grid 396 flattened (XCD-swizzled, m-major: wgid = m*12 + n).
// ---------------------------------------------------------------------------
__global__ __launch_bounds__(1024)
__attribute__((amdgpu_waves_per_eu(4, 8))) void gemm_qkv(
    const unsigned short* __restrict__ Xf, const unsigned short* __restrict__ Wcat,
    const float* __restrict__ bq, const float* __restrict__ bk,
    const float* __restrict__ bv, const unsigned short* __restrict__ XAd,
    const unsigned short* __restrict__ Bccat, const int* __restrict__ idx,
    unsigned short* __restrict__ qh, unsigned short* __restrict__ kh,
    unsigned short* __restrict__ vTg)
{
    // 2 K-tile buffers, each A[256][32] + B[256][32] fp16 = 32 KB -> 64 KB.
    __shared__ unsigned short S[32768];
    const int tid = threadIdx.x;
    const int wgid = xcd_swz(blockIdx.x, 396);
    const int bxn = wgid % 12;           // 0..11
    const int m0 = (wgid / 12) * 256;
    const int p = bxn >> 2;              // projection 0=q 1=k 2=v
    const int n0g = bxn * 256;           // global col in Wcat
    const int nloc0 = (bxn & 3) * 256;   // col within the projection's 1024
    const int lane = tid & 63;
    const int w = tid >> 6;              // wave 0..15
    const int wm = (w >> 2) * 64;        // wave M offset (0..192)
    const int wn = (w & 3) * 64;         // wave N offset (0..192)
    const int l16 = lane & 15;
    const int quad = lane >> 4;
    const int sb = (quad ^ ((l16 >> 1) & 3)) * 8;
    const int aoff = (wm + l16) * 32 + sb;
    const int boff = (wn + l16) * 32 + sb;

    f32x4 acc[4][4];
#pragma unroll
    for (int i = 0; i < 4; ++i)
#pragma unroll
        for (int j = 0; j < 4; ++j) acc[i][j] = (f32x4){0.f, 0.f, 0.f, 0.f};

    // staging: thread covers row tid>>2 (0..255), chunk tid&3 (XOR-swizzled).
    const int srow = tid >> 2;
    const int schk = ((tid & 3) ^ ((srow >> 1) & 3)) * 8;
    const size_t gA = (size_t)(m0 + srow) * DD + schk;
    const size_t gB = (size_t)(n0g + srow) * DD + schk;

    // ---- main K loop: 2-buf double buffer; cross-block TLP hides drain ----
    QKV_STAGE(0, 0);
#pragma unroll 1
    for (int kt = 0; kt < 32; ++kt) {
        GSYNC();
        if (kt < 31) QKV_STAGE((kt + 1) & 1, kt + 1);
        QKV_PHASES(kt & 1);
    }

    // ---- LoRA tail (k=32: 2 experts x 16 r) into buffer 0 ----
    {
        int m_hi = m0 + 255;
        if (m_hi >= MTOT) m_hi = MTOT - 1;
        const int b_first = m0 / SS;
        const int b_last = m_hi / SS;
        const int r = tid >> 2;          // 0..255
        const int cc = tid & 3;          // physical chunk
        const int key = (r >> 1) & 3;
        const int g = cc ^ key;          // logical chunk (expert/half)
        const uint4 z = make_uint4(0, 0, 0, 0);
#pragma unroll 1
        for (int bp = b_first; bp <= b_last; ++bp) {
            const int gm = m0 + r;
            const bool va = (gm < MTOT) && (gm / SS == bp);
            uint4 av = z;
            if (va) {
                const int e = idx[bp * 2 + (g >> 1)];
                av = *(const uint4*)&XAd[(size_t)gm * 384 + p * 128 +
                                         e * 16 + (g & 1) * 8];
            }
            const size_t bo = ((size_t)bp * 3072 + p * 1024 + nloc0 + r) * 32;
            uint4 bv2 = *(const uint4*)&Bccat[bo + g * 8];
            __syncthreads();
            *(uint4*)&S[r * 32 + cc * 8] = av;
            *(uint4*)&S[8192 + r * 32 + cc * 8] = bv2;
            __syncthreads();
            QKV_PHASES(0);
            __syncthreads();
        }
    }

    // ---- epilogue (reuses S; 64KB budget) ----
    unsigned short* Epi = S;
    const float* bias = (p == 0) ? bq : (p == 1) ? bk : bv;
    if (p < 2) {
        // q/k: 4 quarter passes of 64 rows through Epi[64][264] (33.8KB)
        const float alpha = (p == 0) ? 0.125f : 1.0f;
        unsigned short* C = (p == 0) ? qh : kh;
#pragma unroll 1
        for (int qtr = 0; qtr < 4; ++qtr) {
            if ((w >> 2) == qtr) {       // 4 waves own rows qtr*64..+63
#pragma unroll
                for (int j = 0; j < 4; ++j) {
                    const int col = wn + j * 16 + l16;
                    const float bvl = bias[nloc0 + col];
#pragma unroll
                    for (int i = 0; i < 4; ++i) {
                        const int ml = i * 16 + quad * 4;   // local 0..63
#pragma unroll
                        for (int rg = 0; rg < 4; ++rg)
                            Epi[(ml + rg) * 264 + col] =
                                f16b(alpha * (acc[i][j][rg] + bvl));
                    }
                }
            }
            __syncthreads();
            {
                const int r = tid >> 4;          // 0..63
                const int c = (tid & 15) * 16;   // 0..240
                const int m = m0 + qtr * 64 + r;
                if (m < MTOT) {
#pragma unroll
                    for (int k = 0; k < 2; ++k)
                        *(uint4*)&C[(size_t)m * DD + nloc0 + c + k * 8] =
                            *(const uint4*)&Epi[r * 264 + c + k * 8];
                }
            }
            __syncthreads();
        }
    } else {
        // v: transposed epilogue -> vT[(b*16+h)*64+d][t] (Epi 34.8KB)
#pragma unroll 1
        for (int hh = 0; hh < 4; ++hh) {
            if ((w >> 2) == hh) {        // 4 waves covering rows hh*64..+63
#pragma unroll
                for (int j = 0; j < 4; ++j) {
                    const int col = wn + j * 16 + l16;
                    const float bvl = bias[nloc0 + col];
#pragma unroll
                    for (int i = 0; i < 4; ++i) {
                        const int ml = i * 16 + quad * 4;
                        ushort4 pk;
                        pk.x = f16b(acc[i][j][0] + bvl);
                        pk.y = f16b(acc[i][j][1] + bvl);
                        pk.z = f16b(acc[i][j][2] + bvl);
                        pk.w = f16b(acc[i][j][3] + bvl);
                        *(ushort4*)&Epi[col * 68 + ml] = pk;
                    }
                }
            }
            __syncthreads();
            {
                const int tl = tid & 63;
                const int mg = m0 + hh * 64 + tl;
                if (mg < MTOT) {
                    const int bq2 = mg / SS;
                    const int t = mg - bq2 * SS;
#pragma unroll 4
                    for (int k = 0; k < 16; ++k) {
                        const int nll = (tid >> 6) + k * 16;  // 0..255
                        const int d = nloc0 + nll;            // 0..1023
                        vTg[((size_t)(bq2 * HH + (d >> 6)) * HDIM + (d & 63)) *
                                VTS + t] = Epi[nll * 68 + tl];
                    }
                }
            }
            __syncthreads();
        }
    }
}

// ---------------------------------------------------------------------------
// gemm_o: 256x128 tile, 512 thr / 8 waves (4Mx2N of 64x64), 2-buf LDS
// 24KB/buf. grid 264 (XCD-swizzled, m-major); fp32 out.
// ---------------------------------------------------------------------------
#define O_STAGE(BUFI, KT)                                                      \
    do {                                                                       \
        unsigned short* b_ = S + (BUFI) * 12288;                               \
        const int k0_ = (KT) * 32;                                             \
        gl_lds16(Xf + gA1 + k0_, b_ + w * 1024);                               \
        gl_lds16(Xf + gA2 + k0_, b_ + w * 1024 + 512);                         \
        gl_lds16(Wh2 + gB + k0_, b_ + 8192 + w * 512);                         \
    } while (0)

#define O_PHASES(BUFI)                                                         \
    do {                                                                       \
        const unsigned short* Ab_ = S + (BUFI) * 12288;                        \
        const unsigned short* Bb_ = Ab_ + 8192;                                \
        f16x8 af_[4], bf_[4];                                                  \
        _Pragma("unroll") for (int j = 0; j < 4; ++j)                          \
            bf_[j] = *(const f16x8*)&Bb_[boff + j * 512];                      \
        _Pragma("unroll") for (int i = 0; i < 4; ++i)                          \
            af_[i] = *(const f16x8*)&Ab_[aoff + i * 512];                      \
        __builtin_amdgcn_s_setprio(1);                                         \
        _Pragma("unroll") for (int i = 0; i < 4; ++i)                          \
        _Pragma("unroll") for (int j = 0; j < 4; ++j)                          \
            acc[i][j] = __builtin_amdgcn_mfma_f32_16x16x32_f16(                \
                af_[i], bf_[j], acc[i][j], 0, 0, 0);                           \
        __builtin_amdgcn_s_setprio(0);                                         \
    } while (0)

__global__ __launch_bounds__(512)
__attribute__((amdgpu_waves_per_eu(2, 8))) void gemm_o(
    const unsigned short* __restrict__ Xf, const unsigned short* __restrict__ Wh2,
    const float* __restrict__ bias, const unsigned short* __restrict__ XAo,
    const unsigned short* __restrict__ Bco, const int* __restrict__ idx,
    float* __restrict__ Cf)
{
    __shared__ unsigned short S[24576];
    const int tid = threadIdx.x;
    const int wgid = xcd_swz(blockIdx.x, 264);
    const int m0 = (wgid >> 3) * 256;    // 33 m-tiles
    const int n0 = (wgid & 7) * 128;     // 8 n-tiles
    const int lane = tid & 63;
    const int w = tid >> 6;              // wave 0..7
    const int wm = (w >> 1) * 64;        // 0..192
    const int wn = (w & 1) * 64;         // 0..64
    const int l16 = lane & 15;
    const int quad = lane >> 4;
    const int sb = (quad ^ ((l16 >> 1) & 3)) * 8;
    const int aoff = (wm + l16) * 32 + sb;
    const int boff = (wn + l16) * 32 + sb;

    f32x4 acc[4][4];
#pragma unroll
    for (int i = 0; i < 4; ++i)
#pragma unroll
        for (int j = 0; j < 4; ++j) acc[i][j] = (f32x4){0.f, 0.f, 0.f, 0.f};

    const int rowA1 = w * 32 + (lane >> 2);          // 0..255 (first half)
    const int chk = lane & 3;
    const int keyA = (rowA1 >> 1) & 3;
    const size_t gA1 = (size_t)(m0 + rowA1) * DD + (chk ^ keyA) * 8;
    const size_t gA2 = gA1 + (size_t)16 * DD;        // rowA1+16, same key
    const int rowB = w * 16 + (lane >> 2);           // 0..127
    const int keyB = (rowB >> 1) & 3;
    const size_t gB = (size_t)(n0 + rowB) * DD + (chk ^ keyB) * 8;

    O_STAGE(0, 0);
#pragma unroll 1
    for (int kt = 0; kt < 32; ++kt) {
        GSYNC();
        if (kt < 31) O_STAGE((kt + 1) & 1, kt + 1);
        O_PHASES(kt & 1);
    }

    // ---- LoRA tail ----
    {
        int m_hi = m0 + 255;
        if (m_hi >= MTOT) m_hi = MTOT - 1;
        const int b_first = m0 / SS;
        const int b_last = m_hi / SS;
        const int rA = tid >> 1;         // 0..255
        const int b0 = (tid & 1) * 2;
        const int keyTA = (rA >> 1) & 3;
        const int g0 = b0 ^ keyTA, g1 = (b0 + 1) ^ keyTA;
        const int rB = tid >> 2;         // 0..127
        const int ccB = tid & 3;
        const int gBt = ccB ^ ((rB >> 1) & 3);
        const uint4 z = make_uint4(0, 0, 0, 0);
#pragma unroll 1
        for (int bp = b_first; bp <= b_last; ++bp) {
            const int gm = m0 + rA;
            const bool va = (gm < MTOT) && (gm / SS == bp);
            uint4 av0 = z, av1 = z;
            if (va) {
                const int e0 = idx[bp * 2 + (g0 >> 1)];
                const int e1 = idx[bp * 2 + (g1 >> 1)];
                av0 = *(const uint4*)&XAo[(size_t)gm * 128 + e0 * 16 +
                                          (g0 & 1) * 8];
                av1 = *(const uint4*)&XAo[(size_t)gm * 128 + e1 * 16 +
                                          (g1 & 1) * 8];
            }
            const size_t bo = ((size_t)bp * 1024 + n0 + rB) * 32;
            uint4 bv2 = *(const uint4*)&Bco[bo + gBt * 8];
            __syncthreads();
            *(uint4*)&S[rA * 32 + b0 * 8] = av0;
            *(uint4*)&S[rA * 32 + (b0 + 1) * 8] = av1;
            *(uint4*)&S[8192 + rB * 32 + ccB * 8] = bv2;
            __syncthreads();
            O_PHASES(0);
            __syncthreads();
        }
    }

#pragma unroll
    for (int j = 0; j < 4; ++j) {
        const int n = n0 + wn + j * 16 + l16;
        const float bvl = bias[n];
#pragma unroll
        for (int i = 0; i < 4; ++i) {
            const int mb = m0 + wm + i * 16 + quad * 4;
#pragma unroll
            for (int rg = 0; rg < 4; ++rg) {
                const int m = mb + rg;
                if (m < MTOT) Cf[(size_t)m * DD + n] = acc[i][j][rg] + bvl;
            }
        }
    }
}

// ---------------------------------------------------------------------------
// attn_v4: one block per (b,h); K resident (swizzled), V^T staged from
// global vT by uint4 copies; 5 q-tiles of 64; register softmax; fp16 MFMA.
// ---------------------------------------------------------------------------
__global__ __launch_bounds__(512, 1) void attn_v4(
    const unsigned short* __restrict__ qh, const unsigned short* __restrict__ kh,
    const unsigned short* __restrict__ vT, unsigned short* __restrict__ Xf)
{
    __shared__ unsigned short Ks[288 * 64];
    __shared__ unsigned short Vt[64 * VTS];
    __shared__ unsigned short Qs[64 * 64];
    __shared__ unsigned short Ps[64 * 296];
    __shared__ float sredm[2][64];
    __shared__ float sreds[2][64];

    const int tid = threadIdx.x;
    const int h = blockIdx.x, b = blockIdx.y;
    const int cb = h * HDIM;
    const int lane = tid & 63;
    const int w = tid >> 6;
    const int r0 = (w & 3) * 16;
    const int ch = w >> 2;
    const int l16 = lane & 15;
    const int quad = lane >> 4;

    const size_t kbase = (size_t)(b * SS) * DD + cb;
    {
        const int rr = w * 8 + (lane >> 3);
        const int cg = ((lane & 7) ^ (rr & 7)) * 8;
#pragma unroll
        for (int c = 0; c < 4; ++c)
            gl_lds16(kh + kbase + (size_t)(c * 64 + rr) * DD + cg,
                     &Ks[(c * 64 + w * 8) * 64]);
    }
    if (tid < 256) {
        uint4 z = make_uint4(0, 0, 0, 0);
        if (tid < 8) z = *(const uint4*)&kh[kbase + (size_t)256 * DD + tid * 8];
        *(uint4*)&Ks[256 * 64 + tid * 8] = z;
    }
    {
        const size_t vbase = (size_t)(b * HH + h) * HDIM * VTS;
        for (int i = tid; i < 64 * 33; i += 512) {
            const int r = i / 33;
            const int c = i - r * 33;
            uint4 v = *(const uint4*)&vT[vbase + (size_t)r * VTS + c * 8];
            if (c == 32) { v.x &= 0xFFFFu; v.y = 0; v.z = 0; v.w = 0; }
            *(uint4*)&Vt[r * VTS + c * 8] = v;
        }
    }

#pragma unroll 1
    for (int qt = 0; qt < 5; ++qt) {
        const int s0 = qt * 64;
        __syncthreads();
        {
            int sg = s0 + (tid >> 3);
            if (sg > SS - 1) sg = SS - 1;
            const int cg = ((tid & 7) ^ ((tid >> 3) & 7)) * 8;
            gl_lds16(qh + (size_t)(b * SS + sg) * DD + cb + cg,
                     &Qs[(w * 8) * 64]);
        }
        __syncthreads();

        f32x4 lac[9];
#pragma unroll
        for (int ct = 0; ct < 9; ++ct) lac[ct] = (f32x4){0.f, 0.f, 0.f, 0.f};
#pragma unroll
        for (int kc = 0; kc < 2; ++kc) {
            const int sb = ((kc * 4 + quad) ^ (l16 & 7)) * 8;
            f16x8 af = *(const f16x8*)&Qs[(r0 + l16) * 64 + sb];
#pragma unroll
            for (int ct = 0; ct < 9; ++ct) {
                const int c0 = ch * 144 + ct * 16;
                f16x8 bf = *(const f16x8*)&Ks[(c0 + l16) * 64 + sb];
                lac[ct] = __builtin_amdgcn_mfma_f32_16x16x32_f16(
                    af, bf, lac[ct], 0, 0, 0);
            }
        }
#pragma unroll
        for (int ct = 0; ct < 9; ++ct) {
            const int t = ch * 144 + ct * 16 + l16;
            if (t > SS - 1) {
                lac[ct][0] = -1e30f; lac[ct][1] = -1e30f;
                lac[ct][2] = -1e30f; lac[ct][3] = -1e30f;
            }
        }
        float mx[4] = {-1e30f, -1e30f, -1e30f, -1e30f};
#pragma unroll
        for (int ct = 0; ct < 9; ++ct)
#pragma unroll
            for (int i = 0; i < 4; ++i) mx[i] = fmaxf(mx[i], lac[ct][i]);
#pragma unroll
        for (int o = 1; o < 16; o <<= 1)
#pragma unroll
            for (int i = 0; i < 4; ++i)
                mx[i] = fmaxf(mx[i], __shfl_xor(mx[i], o, 16));
        if (l16 == 0)
#pragma unroll
            for (int i = 0; i < 4; ++i) sredm[ch][r0 + quad * 4 + i] = mx[i];
        __syncthreads();
#pragma unroll
        for (int i = 0; i < 4; ++i)
            mx[i] = fmaxf(mx[i], sredm[1 - ch][r0 + quad * 4 + i]);
        float sm[4] = {0.f, 0.f, 0.f, 0.f};
#pragma unroll
        for (int ct = 0; ct < 9; ++ct)
#pragma unroll
            for (int i = 0; i < 4; ++i) {
                float pv = __expf(lac[ct][i] - mx[i]);
                lac[ct][i] = pv;
                sm[i] += pv;
            }
#pragma unroll
        for (int o = 1; o < 16; o <<= 1)
#pragma unroll
            for (int i = 0; i < 4; ++i) sm[i] += __shfl_xor(sm[i], o, 16);
        if (l16 == 0)
#pragma unroll
            for (int i = 0; i < 4; ++i) sreds[ch][r0 + quad * 4 + i] = sm[i];
        __syncthreads();
        float inv[4];
#pragma unroll
        for (int i = 0; i < 4; ++i)
            inv[i] = 1.f / (sm[i] + sreds[1 - ch][r0 + quad * 4 + i]);
#pragma unroll
        for (int ct = 0; ct < 9; ++ct) {
            const int col = ch * 144 + ct * 16 + l16;
#pragma unroll
            for (int i = 0; i < 4; ++i)
                Ps[(r0 + quad * 4 + i) * 296 + col] =
                    f16b(lac[ct][i] * inv[i]);
        }
        __syncthreads();

        f32x4 oacc[2];
        oacc[0] = (f32x4){0.f, 0.f, 0.f, 0.f};
        oacc[1] = (f32x4){0.f, 0.f, 0.f, 0.f};
#pragma unroll
        for (int tt = 0; tt < 9; ++tt) {
            const int t0 = tt * 32;
            f16x8 pf = *(const f16x8*)&Ps[(r0 + l16) * 296 + t0 + quad * 8];
#pragma unroll
            for (int dt = 0; dt < 2; ++dt) {
                f16x8 bvv = *(const f16x8*)&Vt[(ch * 32 + dt * 16 + l16) * VTS +
                                               t0 + quad * 8];
                oacc[dt] = __builtin_amdgcn_mfma_f32_16x16x32_f16(
                    pf, bvv, oacc[dt], 0, 0, 0);
            }
        }
#pragma unroll
        for (int dt = 0; dt < 2; ++dt)
#pragma unroll
            for (int i = 0; i < 4; ++i) {
                const int srow = s0 + r0 + quad * 4 + i;
                if (srow < SS)
                    Xf[(size_t)(b * SS + srow) * DD + cb + ch * 32 + dt * 16 +
                       l16] = f16b(oacc[dt][i]);
            }
    }
}

// ---------------------------------------------------------------------------
extern "C" void kernel_launch(void* const* d_in, const int* in_sizes, int n_in,
                              void* d_out, int out_size, void* d_ws,
                              size_t ws_size, hipStream_t stream)
{
    const float* hidden = (const float*)d_in[0];
    const int* tki = (const int*)d_in[1];
    const float* tkg = (const float*)d_in[2];
    const float* wq = (const float*)d_in[3];
    const float* Aq = (const float*)d_in[4];
    const float* Bq = (const float*)d_in[5];
    const float* bq = (const float*)d_in[6];
    const float* wk = (const float*)d_in[7];
    const float* Ak = (const float*)d_in[8];
    const float* Bk = (const float*)d_in[9];
    const float* bkb = (const float*)d_in[10];
    const float* wv = (const float*)d_in[11];
    const float* Av = (const float*)d_in[12];
    const float* Bv = (const float*)d_in[13];
    const float* bvb = (const float*)d_in[14];
    const float* wo = (const float*)d_in[15];
    const float* Ao = (const float*)d_in[16];
    const float* Bo = (const float*)d_in[17];
    const float* bob = (const float*)d_in[18];
    float* out = (float*)d_out;

    // ---- workspace (~72 MB) ----
    char* ws = (char*)d_ws;
    const size_t NW = (size_t)DD * DD;
    const size_t NA = (size_t)EE * RR * DD;
    unsigned short* Xf = (unsigned short*)ws;    ws += (size_t)MPAD * DD * 2;
    unsigned short* qh = (unsigned short*)ws;    ws += (size_t)MTOT * DD * 2;
    unsigned short* vTg = (unsigned short*)ws;   ws += (size_t)BB * HH * HDIM * VTS * 2;
    unsigned short* Wcat = (unsigned short*)ws;  ws += 3 * NW * 2;
    unsigned short* Who = (unsigned short*)ws;   ws += NW * 2;
    unsigned short* A3 = (unsigned short*)ws;    ws += 3 * NA * 2;
    unsigned short* Ao16 = (unsigned short*)ws;  ws += NA * 2;
    unsigned short* Bccat = (unsigned short*)ws; ws += (size_t)BB * 3072 * 32 * 2;
    unsigned short* Bco = (unsigned short*)ws;   ws += (size_t)BB * 1024 * 32 * 2;
    unsigned short* XAo = (unsigned short*)ws;   ws += (size_t)MTOT * 128 * 2;
    // parked in d_out (dead before gemm_o writes out):
    unsigned short* kh = (unsigned short*)d_out;
    unsigned short* XAd = (unsigned short*)((char*)d_out + (size_t)MTOT * DD * 2);

    prep<<<14080, 256, 0, stream>>>(hidden, wq, wk, wv, wo, Aq, Ak, Av, Ao,
                                    Bq, Bk, Bv, Bo, tki, tkg, Xf, Wcat, Who,
                                    A3, Ao16, Bccat, Bco);
    gemm_xa<<<dim3(3, 65), 256, 0, stream>>>(Xf, A3, A3 + NA, A3 + 2 * NA,
                                             XAd, 384);
    gemm_qkv<<<396, 1024, 0, stream>>>(Xf, Wcat, bq, bkb, bvb, XAd,
                                       Bccat, tki, qh, kh, vTg);
    attn_v4<<<dim3(HH, BB), 512, 0, stream>>>(qh, kh, vTg, Xf);
    gemm_xa<<<dim3(1, 65), 256, 0, stream>>>(Xf, Ao16, Ao16, Ao16, XAo, 128);
    gemm_o<<<264, 512, 0, stream>>>(Xf, Who, bob, XAo, Bco, tki, out);
}